// Round 1
// baseline (13980.797 us; speedup 1.0000x reference)
//
#include <hip/hip_runtime.h>
#include <hip/hip_bf16.h>
#include <math.h>

// LSTMConv: gather bottom-right pixel of each 2x2 patch -> per-pixel LSTM over
// time N=32 -> per-step FC 128->64.
//
// Structure: 256 blocks x 256 threads. Block owns BP=64 consecutive p
// (patch pixels). lane (0..63) = local p; wave (0..3) owns 32 hidden units.
// h kept in LDS [64][129] (pad -> 2-way bank alias, free); c in registers.
// All weight indices are wave-uniform (readfirstlane) -> scalar s_load
// broadcasts; each inner FMA is v_fmac_f32 with one SGPR operand.

#define T_STEPS 32
#define C_IN    64
#define HID     128
#define P_TOT   16384
#define OUT_F   64
#define BP      64              // p per block
#define NBLK    (P_TOT / BP)    // 256
#define NTHR    256
#define JPW     32              // hidden units per wave

__device__ __forceinline__ float sigmoidf_(float x) {
    return 1.0f / (1.0f + __expf(-x));
}
__device__ __forceinline__ float tanhf_(float x) {
    // sign-safe tanh via exp of negative argument (no overflow/NaN)
    float ax = fabsf(x);
    float e  = __expf(-2.0f * ax);
    float t  = 1.0f - 2.0f * e / (1.0f + e);
    return copysignf(t, x);
}

__global__ __launch_bounds__(NTHR, 1) void lstmconv_kernel(
    const float* __restrict__ feats,
    const float* __restrict__ W_ih,
    const float* __restrict__ W_hh,
    const float* __restrict__ b_ih,
    const float* __restrict__ b_hh,
    const float* __restrict__ fc_w,
    const float* __restrict__ fc_b,
    float* __restrict__ out)
{
    __shared__ float h_s[BP][HID + 1];   // 64*129*4 = 33 KB
    __shared__ float x_s[BP][C_IN + 1];  // 64*65*4  = 16.6 KB

    const int tid  = threadIdx.x;
    const int lane = tid & 63;
    const int wave = tid >> 6;
    const int j0   = __builtin_amdgcn_readfirstlane(wave * JPW);
    const int o0   = __builtin_amdgcn_readfirstlane(wave * 16);
    const int p0   = blockIdx.x * BP;

    // zero h state
    for (int i = tid; i < BP * (HID + 1); i += NTHR)
        (&h_s[0][0])[i] = 0.0f;

    float c_reg[JPW];
    #pragma unroll
    for (int jj = 0; jj < JPW; ++jj) c_reg[jj] = 0.0f;

    __syncthreads();

    for (int t = 0; t < T_STEPS; ++t) {
        // ---- gather this timestep's inputs: x_s[p_l][c] = feats[t,c,2r+1,2col+1]
        #pragma unroll
        for (int i = tid; i < BP * C_IN; i += NTHR) {
            int p_l = i & (BP - 1);
            int c   = i >> 6;
            int p   = p0 + p_l;
            int row = 2 * (p >> 7) + 1;
            int col = 2 * (p & 127) + 1;
            x_s[p_l][c] = feats[(((size_t)t * C_IN + c) << 16) + (row << 8) + col];
        }
        __syncthreads();   // B1: x_s ready (h_s still holds h_{t-1})

        // ---- gates: acc[gi][jj] = b + W_ih@x + W_hh@h  (gate rows gi*128+j)
        float acc[4][JPW];
        #pragma unroll
        for (int gi = 0; gi < 4; ++gi) {
            #pragma unroll
            for (int jj = 0; jj < JPW; ++jj) {
                int g = gi * HID + j0 + jj;
                acc[gi][jj] = b_ih[g] + b_hh[g];
            }
        }

        #pragma unroll 2
        for (int k = 0; k < HID; ++k) {
            float hk = h_s[lane][k];
            #pragma unroll
            for (int gi = 0; gi < 4; ++gi)
                #pragma unroll
                for (int jj = 0; jj < JPW; ++jj)
                    acc[gi][jj] = fmaf(W_hh[(gi * HID + j0 + jj) * HID + k], hk, acc[gi][jj]);
        }
        #pragma unroll 2
        for (int k = 0; k < C_IN; ++k) {
            float xk = x_s[lane][k];
            #pragma unroll
            for (int gi = 0; gi < 4; ++gi)
                #pragma unroll
                for (int jj = 0; jj < JPW; ++jj)
                    acc[gi][jj] = fmaf(W_ih[(gi * HID + j0 + jj) * C_IN + k], xk, acc[gi][jj]);
        }

        // ---- LSTM cell update (gate order i,f,g,o)
        float hval[JPW];
        #pragma unroll
        for (int jj = 0; jj < JPW; ++jj) {
            float ig = sigmoidf_(acc[0][jj]);
            float fg = sigmoidf_(acc[1][jj]);
            float gg = tanhf_(acc[2][jj]);
            float og = sigmoidf_(acc[3][jj]);
            float cv = fg * c_reg[jj] + ig * gg;
            c_reg[jj] = cv;
            hval[jj]  = og * tanhf_(cv);
        }

        __syncthreads();   // B2: everyone done reading h_{t-1}
        #pragma unroll
        for (int jj = 0; jj < JPW; ++jj)
            h_s[lane][j0 + jj] = hval[jj];
        __syncthreads();   // B3: h_t complete

        // ---- FC on h_t: out[t, o, p], wave owns 16 of 64 outputs
        float acc_o[16];
        #pragma unroll
        for (int oo = 0; oo < 16; ++oo)
            acc_o[oo] = fc_b[o0 + oo];

        #pragma unroll 4
        for (int k = 0; k < HID; ++k) {
            float hk = h_s[lane][k];
            #pragma unroll
            for (int oo = 0; oo < 16; ++oo)
                acc_o[oo] = fmaf(fc_w[(o0 + oo) * HID + k], hk, acc_o[oo]);
        }
        #pragma unroll
        for (int oo = 0; oo < 16; ++oo)
            out[(((size_t)t * OUT_F + o0 + oo) << 14) + p0 + lane] = acc_o[oo];
        // next iteration's x_s/h_s writes are separated from this iteration's
        // reads by B1/B2 of the next loop pass.
    }
}

extern "C" void kernel_launch(void* const* d_in, const int* in_sizes, int n_in,
                              void* d_out, int out_size, void* d_ws, size_t ws_size,
                              hipStream_t stream) {
    const float* feats = (const float*)d_in[0];
    const float* W_ih  = (const float*)d_in[1];
    const float* W_hh  = (const float*)d_in[2];
    const float* b_ih  = (const float*)d_in[3];
    const float* b_hh  = (const float*)d_in[4];
    const float* fc_w  = (const float*)d_in[5];
    const float* fc_b  = (const float*)d_in[6];
    float* out = (float*)d_out;

    lstmconv_kernel<<<NBLK, NTHR, 0, stream>>>(feats, W_ih, W_hh, b_ih, b_hh,
                                               fc_w, fc_b, out);
}

// Round 2
// 209.459 us; speedup vs baseline: 66.7473x; 66.7473x over previous
//
#include <hip/hip_runtime.h>
#include <stdint.h>
#include <math.h>

// LSTMConv via MFMA: per t-step, gates(512x64) = W(512x192) @ [x;h](192x64)
// with mfma_f32_16x16x32_bf16; weights live in VGPRs (loaded once);
// [x;h] staged in LDS bf16; FC(64x128) also MFMA, split across 8 waves.
//
// Layout conventions (16x16x32): A: row=lane&15, k = 8*(lane>>4)+e (e=0..7)
//                                B: col=lane&15, k = same map
//                                C/D: col=lane&15, row=(lane>>4)*4+reg  [verified]
// Any error in the shared k-map cancels between A and B (k is summed).

#define T_STEPS 32
#define C_IN    64
#define HID     128
#define P_TOT   16384
#define OUT_F   64
#define BP      64
#define NBLK    (P_TOT / BP)   // 256
#define NTHR    512            // 8 waves
#define PADK    196            // xh row stride (bf16 elems); k 0..63 = x, 64..191 = h
#define FCPAD   132

typedef __attribute__((ext_vector_type(8))) short short8_t;
typedef __attribute__((ext_vector_type(4))) short short4_t;
typedef __attribute__((ext_vector_type(4))) float float4_t;

__device__ __forceinline__ short f2bf(float f) {
    uint32_t u = __builtin_bit_cast(uint32_t, f);
    u += 0x7fff + ((u >> 16) & 1);   // round-to-nearest-even
    return (short)(u >> 16);
}
__device__ __forceinline__ float sigm(float x) {
    return __builtin_amdgcn_rcpf(1.0f + __expf(-x));
}
__device__ __forceinline__ float tanh_(float x) {
    float ax = fabsf(x);
    float e  = __expf(-2.0f * ax);
    float t  = (1.0f - e) * __builtin_amdgcn_rcpf(1.0f + e);
    return copysignf(t, x);
}

__global__ __launch_bounds__(NTHR, 2) void lstmconv_mfma(
    const float* __restrict__ feats,
    const float* __restrict__ W_ih,
    const float* __restrict__ W_hh,
    const float* __restrict__ b_ih,
    const float* __restrict__ b_hh,
    const float* __restrict__ fc_w,
    const float* __restrict__ fc_b,
    float* __restrict__ out)
{
    __shared__ __align__(16) short xh[BP][PADK];      // 25.1 KB, [p][k]
    __shared__ __align__(16) float bias_s[4 * HID];   // 2 KB
    __shared__ __align__(16) short fc_s[OUT_F][FCPAD];// 16.9 KB

    const int tid  = threadIdx.x;
    const int lane = tid & 63;
    const int w    = tid >> 6;       // wave 0..7; owns j in [16w, 16w+16)
    const int i16  = lane & 15;
    const int g4   = lane >> 4;
    const int p0   = blockIdx.x * BP;

    // ---------- one-time init ----------
    for (int i = tid; i < BP * PADK / 2; i += NTHR)
        ((uint32_t*)&xh[0][0])[i] = 0u;              // h region must start 0
    bias_s[tid] = b_ih[tid] + b_hh[tid];             // 512 == NTHR
    for (int i = tid; i < OUT_F * HID; i += NTHR)
        fc_s[i >> 7][i & 127] = f2bf(fc_w[i]);

    // W fragments (A operand), persistent in VGPRs: wfrag[gate][ktile]
    // gate row = 128*gi + 16*w + i16 ; k = 32*kt + 8*g4 + e  (kt<2 -> W_ih)
    short8_t wfrag[4][6];
    #pragma unroll
    for (int gi = 0; gi < 4; ++gi) {
        int row = 128 * gi + 16 * w + i16;
        #pragma unroll
        for (int kt = 0; kt < 6; ++kt) {
            int kk = 32 * kt + 8 * g4;
            const float* src = (kt < 2) ? &W_ih[row * C_IN + kk]
                                        : &W_hh[row * HID + (kk - 64)];
            short8_t f;
            #pragma unroll
            for (int e = 0; e < 8; ++e) f[e] = f2bf(src[e]);
            wfrag[gi][kt] = f;
        }
    }

    // FC assignment: wave handles m-tile m2=w&3 (out rows 16*m2..+16) and
    // n-tiles {ntb, ntb+1}, ntb = (w>>2)*2.
    const int m2  = w & 3;
    const int ntb = (w >> 2) << 1;
    const float4_t fcb = *(const float4_t*)&fc_b[16 * m2 + 4 * g4];

    float4_t c[4];
    #pragma unroll
    for (int nt = 0; nt < 4; ++nt) c[nt] = (float4_t){0.f, 0.f, 0.f, 0.f};

    const int prow  = 2 * (p0 >> 7) + 1;
    const int pcol0 = 2 * (p0 & 127) + 1;

    __syncthreads();

    for (int t = 0; t < T_STEPS; ++t) {
        // ---- Phase G: gather x_t -> xh[:, 0:64] (bottom-right pixel of patch)
        {
            int p_l = tid & 63;
            int c0  = tid >> 6;
            #pragma unroll
            for (int q = 0; q < 8; ++q) {
                int cc = c0 + 8 * q;
                float v = feats[(((size_t)(t * C_IN + cc)) << 16)
                                + prow * 256 + pcol0 + 2 * p_l];
                xh[p_l][cc] = f2bf(v);
            }
        }
        __syncthreads();   // B1: x_t ready (h region holds h_{t-1})

        // ---- Phase A: gates = bias + W @ [x;h]
        float4_t acc[4][4];
        #pragma unroll
        for (int gi = 0; gi < 4; ++gi) {
            float4_t bv = *(const float4_t*)&bias_s[128 * gi + 16 * w + 4 * g4];
            #pragma unroll
            for (int nt = 0; nt < 4; ++nt) acc[gi][nt] = bv;
        }
        #pragma unroll
        for (int kt = 0; kt < 6; ++kt) {
            short8_t bfrag[4];
            #pragma unroll
            for (int nt = 0; nt < 4; ++nt) {
                int p  = 16 * nt + i16;
                int kb = 32 * kt + 8 * g4;
                union { short8_t v8; short4_t v4[2]; } u;
                u.v4[0] = *(const short4_t*)&xh[p][kb];
                u.v4[1] = *(const short4_t*)&xh[p][kb + 4];
                bfrag[nt] = u.v8;
            }
            #pragma unroll
            for (int gi = 0; gi < 4; ++gi)
                #pragma unroll
                for (int nt = 0; nt < 4; ++nt)
                    acc[gi][nt] = __builtin_amdgcn_mfma_f32_16x16x32_bf16(
                        wfrag[gi][kt], bfrag[nt], acc[gi][nt], 0, 0, 0);
        }

        // ---- Phase U: LSTM cell update (gate order i,f,g,o)
        short4_t hpack[4];
        #pragma unroll
        for (int nt = 0; nt < 4; ++nt) {
            float4_t cv = c[nt];
            short4_t hp;
            #pragma unroll
            for (int r = 0; r < 4; ++r) {
                float ig = sigm(acc[0][nt][r]);
                float fg = sigm(acc[1][nt][r]);
                float gg = tanh_(acc[2][nt][r]);
                float og = sigm(acc[3][nt][r]);
                float cn = fg * cv[r] + ig * gg;
                cv[r] = cn;
                hp[r] = f2bf(og * tanh_(cn));
            }
            c[nt] = cv;
            hpack[nt] = hp;
        }
        __syncthreads();   // B2: all reads of h_{t-1} complete

        // ---- Phase W: h_t -> xh[:, 64:192]  (j = 16w + 4*g4 + r)
        #pragma unroll
        for (int nt = 0; nt < 4; ++nt) {
            int p = 16 * nt + i16;
            *(short4_t*)&xh[p][64 + 16 * w + 4 * g4] = hpack[nt];
        }
        __syncthreads();   // B3: h_t complete

        // ---- Phase F: out_t = fc_b + fc_w @ h_t
        {
            float4_t facc[2];
            facc[0] = fcb; facc[1] = fcb;
            #pragma unroll
            for (int kt = 0; kt < 4; ++kt) {
                int kb = 32 * kt + 8 * g4;
                union { short8_t v8; short4_t v4[2]; } ua;
                ua.v4[0] = *(const short4_t*)&fc_s[16 * m2 + i16][kb];
                ua.v4[1] = *(const short4_t*)&fc_s[16 * m2 + i16][kb + 4];
                #pragma unroll
                for (int nj = 0; nj < 2; ++nj) {
                    int p = 16 * (ntb + nj) + i16;
                    union { short8_t v8; short4_t v4[2]; } ub;
                    ub.v4[0] = *(const short4_t*)&xh[p][64 + kb];
                    ub.v4[1] = *(const short4_t*)&xh[p][64 + kb + 4];
                    facc[nj] = __builtin_amdgcn_mfma_f32_16x16x32_bf16(
                        ua.v8, ub.v8, facc[nj], 0, 0, 0);
                }
            }
            #pragma unroll
            for (int nj = 0; nj < 2; ++nj)
                #pragma unroll
                for (int r = 0; r < 4; ++r)
                    out[((size_t)(t * OUT_F + 16 * m2 + 4 * g4 + r) << 14)
                        + p0 + 16 * (ntb + nj) + i16] = facc[nj][r];
        }
        // next G(t+1) writes x region only; h region reads (F) are disjoint.
    }
}

extern "C" void kernel_launch(void* const* d_in, const int* in_sizes, int n_in,
                              void* d_out, int out_size, void* d_ws, size_t ws_size,
                              hipStream_t stream) {
    const float* feats = (const float*)d_in[0];
    const float* W_ih  = (const float*)d_in[1];
    const float* W_hh  = (const float*)d_in[2];
    const float* b_ih  = (const float*)d_in[3];
    const float* b_hh  = (const float*)d_in[4];
    const float* fc_w  = (const float*)d_in[5];
    const float* fc_b  = (const float*)d_in[6];
    float* out = (float*)d_out;

    lstmconv_mfma<<<NBLK, NTHR, 0, stream>>>(feats, W_ih, W_hh, b_ih, b_hh,
                                             fc_w, fc_b, out);
}